// Round 8
// baseline (71.230 us; speedup 1.0000x reference)
//
#include <hip/hip_runtime.h>
#include <hip/hip_cooperative_groups.h>
#include <float.h>

namespace cg = cooperative_groups;

#define NB 68                 // padded bins (64 + 2*2)
#define NJ (NB * NB)          // 4624 joint bins
#define BX 125                // blocks per batch: 125*1024*4 = 512000 voxels
#define TPB 1024
#define SCALE 2097152.0f      // 2^21 fixed-point scale
#define INV_SCALE (1.0 / 2097152.0)

// ws layout (bytes):
// [64 .. 64+2*128*16)  P: per-block minmax partials, float4 {smx,smn,tmx,tmn}
// [4160 .. +2*NJ*8)    J: u64 fixed-point joint accumulators [b][NJ]

__device__ __forceinline__ float bspl(float d) {
    float ad = fabsf(d);
    float a = (3.0f * ad * ad * ad - 6.0f * ad * ad + 4.0f) * (1.0f / 6.0f);
    float t = 2.0f - ad;
    float c = t * t * t * (1.0f / 6.0f);
    return ad < 1.0f ? a : (ad < 2.0f ? c : 0.0f);
}

__device__ __forceinline__ void vox1(float sv, float tv, unsigned* jh,
                                     float spad, float sinv, float tpad,
                                     float tinv) {
    float posS = (sv - spad) * sinv;
    float fS = floorf(posS);
    fS = fminf(fmaxf(fS, 2.0f), 65.0f);
    int si = (int)fS - 1;
    float dS = posS - fS;
    float a[4] = {bspl(dS + 1.0f), bspl(dS), bspl(dS - 1.0f), bspl(dS - 2.0f)};

    float posT = (tv - tpad) * tinv;
    float fT = floorf(posT);
    fT = fminf(fmaxf(fT, 2.0f), 65.0f);
    int ti = (int)fT - 1;
    float dT = posT - fT;
    float bb[4] = {bspl(dT + 1.0f), bspl(dT), bspl(dT - 1.0f), bspl(dT - 2.0f)};

    unsigned* base = jh + si * NB + ti;
#pragma unroll
    for (int r = 0; r < 4; ++r) {
#pragma unroll
        for (int c = 0; c < 4; ++c) {
            unsigned q = (unsigned)(a[r] * bb[c] * SCALE + 0.5f);
            atomicAdd(&base[r * NB + c], q);
        }
    }
}

// One cooperative kernel. Voxels stay in registers across grid.sync(), so
// inputs are read from HBM exactly once. All accumulation is integer
// (order-independent -> deterministic). No threadfence/ticket (that cost
// ~30us in r7); grid.sync() provides the ordering.
__global__ __launch_bounds__(TPB) void k_all(const float* __restrict__ src,
                                             const float* __restrict__ tgt,
                                             float4* __restrict__ P,
                                             unsigned long long* __restrict__ J,
                                             float* __restrict__ out, int n4) {
    __shared__ unsigned lh[2 * NJ];
    __shared__ float red[16][4];
    __shared__ float pmm[8], mmv[4];
    __shared__ float rs[NB], cs[NB], red16[16];

    const int tid = threadIdx.x;
    const int bx = blockIdx.x;
    const int b = blockIdx.y;
    cg::grid_group grid = cg::this_grid();

    // ---- phase 1: load voxels (register-cached), minmax partials, zero J
    const int i = bx * TPB + tid;
    const bool valid = i < n4;            // always true for 80^3 (125*1024==n4)
    float4 sv = make_float4(0.f, 0.f, 0.f, 0.f);
    float4 tv = make_float4(0.f, 0.f, 0.f, 0.f);
    float smx = -FLT_MAX, smn = FLT_MAX, tmx = -FLT_MAX, tmn = FLT_MAX;
    if (valid) {
        sv = ((const float4*)src)[(size_t)b * n4 + i];
        tv = ((const float4*)tgt)[(size_t)b * n4 + i];
        smx = fmaxf(fmaxf(sv.x, sv.y), fmaxf(sv.z, sv.w));
        smn = fminf(fminf(sv.x, sv.y), fminf(sv.z, sv.w));
        tmx = fmaxf(fmaxf(tv.x, tv.y), fmaxf(tv.z, tv.w));
        tmn = fminf(fminf(tv.x, tv.y), fminf(tv.z, tv.w));
    }
    const int gid = (b * BX + bx) * TPB + tid;
    if (gid < 2 * NJ) J[gid] = 0ull;

#pragma unroll
    for (int m = 1; m < 64; m <<= 1) {
        smx = fmaxf(smx, __shfl_xor(smx, m));
        smn = fminf(smn, __shfl_xor(smn, m));
        tmx = fmaxf(tmx, __shfl_xor(tmx, m));
        tmn = fminf(tmn, __shfl_xor(tmn, m));
    }
    const int wave = tid >> 6;
    if ((tid & 63) == 0) {
        red[wave][0] = smx;
        red[wave][1] = smn;
        red[wave][2] = tmx;
        red[wave][3] = tmn;
    }
    __syncthreads();
    if (tid == 0) {
#pragma unroll
        for (int k = 1; k < 16; ++k) {
            smx = fmaxf(smx, red[k][0]);
            smn = fminf(smn, red[k][1]);
            tmx = fmaxf(tmx, red[k][2]);
            tmn = fminf(tmn, red[k][3]);
        }
        P[b * 128 + bx] = make_float4(smx, smn, tmx, tmn);
    }
    grid.sync();

    // ---- phase 2: reduce P inline, LDS joint histogram, u64 flush
    {
        float a = -FLT_MAX, c = FLT_MAX, d = -FLT_MAX, e = FLT_MAX;
        if (tid < 128) {
            if (tid < BX) {
                float4 v = P[b * 128 + tid];
                a = v.x; c = v.y; d = v.z; e = v.w;
            }
#pragma unroll
            for (int m = 1; m < 64; m <<= 1) {
                a = fmaxf(a, __shfl_xor(a, m));
                c = fminf(c, __shfl_xor(c, m));
                d = fmaxf(d, __shfl_xor(d, m));
                e = fminf(e, __shfl_xor(e, m));
            }
            if ((tid & 63) == 0) {
                int w = tid >> 6;
                pmm[w * 4 + 0] = a;
                pmm[w * 4 + 1] = c;
                pmm[w * 4 + 2] = d;
                pmm[w * 4 + 3] = e;
            }
        }
        uint4* z4 = (uint4*)lh;
        const uint4 zz = make_uint4(0u, 0u, 0u, 0u);
        for (int k = tid; k < (2 * NJ) / 4; k += TPB) z4[k] = zz;
        __syncthreads();
        if (tid == 0) {
            mmv[0] = fmaxf(pmm[0], pmm[4]);   // smx
            mmv[1] = fminf(pmm[1], pmm[5]);   // smn
            mmv[2] = fmaxf(pmm[2], pmm[6]);   // tmx
            mmv[3] = fminf(pmm[3], pmm[7]);   // tmn
        }
        __syncthreads();
    }

    const float sbw = (mmv[0] - mmv[1]) * (1.0f / 64.0f);
    const float tbw = (mmv[2] - mmv[3]) * (1.0f / 64.0f);
    const float sinv = 1.0f / sbw, tinv = 1.0f / tbw;
    const float spad = mmv[1] - 2.0f * sbw;
    const float tpad = mmv[3] - 2.0f * tbw;

    unsigned* jh = lh + (tid >> 9) * NJ;   // waves 0-7 / 8-15 copies
    if (valid) {
        vox1(sv.x, tv.x, jh, spad, sinv, tpad, tinv);
        vox1(sv.y, tv.y, jh, spad, sinv, tpad, tinv);
        vox1(sv.z, tv.z, jh, spad, sinv, tpad, tinv);
        vox1(sv.w, tv.w, jh, spad, sinv, tpad, tinv);
    }
    __syncthreads();

    unsigned long long* Jb = J + (size_t)b * NJ;
    for (int k = tid; k < NJ; k += TPB) {
        unsigned long long s = (unsigned long long)lh[k] + lh[NJ + k];
        if (s) atomicAdd(&Jb[k], s);
    }
    grid.sync();

    // ---- phase 3: block (0,b) finalizes batch b (2 blocks in parallel)
    if (bx != 0) return;
    float* jf = (float*)lh;               // reuse LDS
    float part = 0.0f;
    for (int k = tid; k < NJ; k += TPB) {
        unsigned long long v = __hip_atomic_load(&Jb[k], __ATOMIC_RELAXED,
                                                 __HIP_MEMORY_SCOPE_AGENT);
        float f = (float)((double)v * INV_SCALE);
        jf[k] = f;
        part += f;
    }
#pragma unroll
    for (int m = 1; m < 64; m <<= 1) part += __shfl_xor(part, m);
    if ((tid & 63) == 0) red16[tid >> 6] = part;
    __syncthreads();

    if (tid < NB) {                        // row sums -> source hist
        float s = 0.0f;
        for (int j = 0; j < NB; ++j) s += jf[tid * NB + j];
        rs[tid] = s;
    }
    if (tid >= 128 && tid < 128 + NB) {    // col sums -> target hist
        int c = tid - 128;
        float s = 0.0f;
        for (int r = 0; r < NB; ++r) s += jf[r * NB + c];
        cs[c] = s;
    }
    __syncthreads();

    float jsum = 0.0f;
#pragma unroll
    for (int k = 0; k < 16; ++k) jsum += red16[k];
    float ssum = 0.0f, tsum = 0.0f;
    for (int k = 0; k < NB; ++k) ssum += rs[k];
    for (int k = 0; k < NB; ++k) tsum += cs[k];
    const float sden = fmaxf(ssum, 1e-8f);
    const float tden = fmaxf(tsum, 1e-8f);
    const float jden = fmaxf(jsum, 1e-8f);

    if (tid < NB) out[b * NB + tid] = rs[tid] / sden;
    if (tid >= 128 && tid < 128 + NB)
        out[2 * NB + b * NB + (tid - 128)] = cs[tid - 128] / tden;
    for (int k = tid; k < NJ; k += TPB)
        out[4 * NB + b * NJ + k] = jf[k] / jden;
}

extern "C" void kernel_launch(void* const* d_in, const int* in_sizes, int n_in,
                              void* d_out, int out_size, void* d_ws,
                              size_t ws_size, hipStream_t stream) {
    const float* src = (const float*)d_in[0];
    const float* tgt = (const float*)d_in[1];
    float* out = (float*)d_out;
    float4* P = (float4*)((char*)d_ws + 64);
    unsigned long long* J = (unsigned long long*)((char*)d_ws + 4160);
    int n4 = (in_sizes[0] / 2) / 4;        // 128000

    void* args[] = {(void*)&src, (void*)&tgt, (void*)&P, (void*)&J,
                    (void*)&out, (void*)&n4};
    hipLaunchCooperativeKernel((const void*)k_all, dim3(BX, 2), dim3(TPB),
                               args, 0, stream);
}